// Round 10
// baseline (728.528 us; speedup 1.0000x reference)
//
#include <hip/hip_runtime.h>
#include <math.h>

#define MAXN_P 0.996f   // (1 - PROJ_EPS)/sqrt(c), c=1

typedef unsigned short bfraw;
typedef __attribute__((ext_vector_type(8))) short bf16x8;
typedef __attribute__((ext_vector_type(4))) float f32x4;

__device__ __forceinline__ float wred(float v){
  #pragma unroll
  for(int o=32;o>0;o>>=1) v += __shfl_xor(v,o,64);
  return v;
}
template<int W>
__device__ __forceinline__ float gredw(float v){
  #pragma unroll
  for(int o=W/2;o>0;o>>=1) v += __shfl_xor(v,o,64);
  return v;
}
__device__ __forceinline__ float artanh_c(float x){
  x = fminf(fmaxf(x, -1.0f+1e-7f), 1.0f-1e-7f);
  return atanhf(x);
}
__device__ __forceinline__ float sel4(float4 w, int g){
  float ab = (g&1) ? w.y : w.x;
  float cd = (g&1) ? w.w : w.z;
  return (g&2) ? cd : ab;
}
__device__ __forceinline__ bfraw f2bf(float f){
  unsigned u = __float_as_uint(f);
  unsigned r = (u + 0x7fffu + ((u>>16)&1u)) >> 16;   // RNE
  return (bfraw)r;
}
__device__ __forceinline__ float bflo(unsigned u){ return __uint_as_float(u<<16); }
__device__ __forceinline__ float bfhi(unsigned u){ return __uint_as_float(u & 0xffff0000u); }

__device__ __forceinline__ void acc8(float* a, float w, uint4 u){
  a[0]=fmaf(w, bflo(u.x), a[0]); a[1]=fmaf(w, bfhi(u.x), a[1]);
  a[2]=fmaf(w, bflo(u.y), a[2]); a[3]=fmaf(w, bfhi(u.y), a[3]);
  a[4]=fmaf(w, bflo(u.z), a[4]); a[5]=fmaf(w, bfhi(u.z), a[5]);
  a[6]=fmaf(w, bflo(u.w), a[6]); a[7]=fmaf(w, bfhi(u.w), a[7]);
}
__device__ __forceinline__ void acc4(float* a, float w, uint2 u){
  a[0]=fmaf(w, bflo(u.x), a[0]); a[1]=fmaf(w, bfhi(u.x), a[1]);
  a[2]=fmaf(w, bflo(u.y), a[2]); a[3]=fmaf(w, bfhi(u.y), a[3]);
}

// post_spmm chain: u -> proj(expmap0(u)) -> relu(logmap0) -> proj(expmap0); norms over W lanes
template<int W, int K>
__device__ __forceinline__ float postK(const float* u, float* h){
  float ss = 0.f;
  #pragma unroll
  for(int k=0;k<K;k++) ss += u[k]*u[k];
  ss = gredw<W>(ss);
  float un = fmaxf(sqrtf(ss), 1e-15f);
  float t1 = tanhf(un);
  float sc = t1/un;
  float pn = t1;
  if (pn > MAXN_P){ sc *= MAXN_P/pn; pn = MAXN_P; }
  float ln = fmaxf(pn, 1e-15f);
  float m = sc * (artanh_c(ln)/ln);
  float v[K]; float vs = 0.f;
  #pragma unroll
  for(int k=0;k<K;k++){ v[k] = fmaxf(u[k]*m, 0.f); vs += v[k]*v[k]; }
  vs = gredw<W>(vs);
  float vn = fmaxf(sqrtf(vs), 1e-15f);
  float t2 = tanhf(vn);
  float qs = t2/vn;
  float qn = t2;
  if (qn > MAXN_P){ qs *= MAXN_P/qn; qn = MAXN_P; }
  #pragma unroll
  for(int k=0;k<K;k++) h[k] = v[k]*qs;
  return qn;
}

// ---------------- fused prologue: exp0 | hist | w2bf(W0) | w2bf(W1) | hb ----------------
__global__ __launch_bounds__(256) void k_prologue(
    const float* __restrict__ x, bfraw* __restrict__ h0, float* __restrict__ n0, int N,
    const int* __restrict__ dst, int* __restrict__ cnt, int E,
    const float* __restrict__ W0, bfraw* __restrict__ w0b, int nW0,
    const float* __restrict__ W1, bfraw* __restrict__ w1b, int nW1,
    const float* __restrict__ b0, const float* __restrict__ b1,
    float* __restrict__ hb0, float* __restrict__ hb1, int HID, int DIM,
    int RB, int HIST, int W0B, int W1B)
{
  int b = blockIdx.x;
  int tid = threadIdx.x;
  if (b < RB){
    int wid = (b*256 + tid)>>6;
    int lane = tid & 63;
    if (wid >= N) return;
    const float* r = x + (size_t)wid*128;
    float u0 = r[lane], u1 = r[lane+64];
    float ss = wred(u0*u0 + u1*u1);
    float un = fmaxf(sqrtf(ss), 1e-15f);
    float tn = tanhf(un);
    float sc = tn/un;
    float pn = tn;
    if (pn > MAXN_P){ sc *= MAXN_P/pn; pn = MAXN_P; }
    h0[(size_t)wid*128 + lane]      = f2bf(u0*sc);
    h0[(size_t)wid*128 + lane + 64] = f2bf(u1*sc);
    if (lane == 0) n0[wid] = pn;
    return;
  }
  b -= RB;
  if (b < HIST){
    int e = b*256 + tid;
    if (e < E) atomicAdd(&cnt[dst[e]], 1);
    return;
  }
  b -= HIST;
  if (b < W0B){
    int i = b*256 + tid;
    if (i < nW0) w0b[i] = f2bf(W0[i]);
    return;
  }
  b -= W0B;
  if (b < W1B){
    int i = b*256 + tid;
    if (i < nW1) w1b[i] = f2bf(W1[i]);
    return;
  }
  b -= W1B;
  {
    if (tid >= 64) return;
    int layer = b >> 2, br = b & 3;
    int D = layer ? DIM : HID;
    const float* bb = layer ? (b1 + (size_t)br*DIM) : (b0 + (size_t)br*HID);
    float* o        = layer ? (hb1 + (size_t)br*DIM) : (hb0 + (size_t)br*HID);
    float v0 = (tid < D) ? bb[tid] : 0.f;
    float v1 = (tid+64 < D) ? bb[tid+64] : 0.f;
    float ss = wred(v0*v0 + v1*v1);
    float n = fmaxf(sqrtf(ss), 1e-15f);
    float tn = tanhf(n);
    float sc = tn/n;
    if (tn > MAXN_P) sc *= MAXN_P/tn;
    if (tid < D)    o[tid]    = v0*sc;
    if (tid+64 < D) o[tid+64] = v1*sc;
  }
}

// ---------------- hierarchical scan: cnt[N] -> rowptr[N+1], cursor[N] ----------------
__global__ __launch_bounds__(256) void k_scan1(const int* __restrict__ cnt, int* __restrict__ bsum, int N){
  __shared__ int sh[256];
  int base = blockIdx.x*2048;
  int tid = threadIdx.x;
  int loc = 0;
  #pragma unroll
  for(int j=0;j<8;j++){
    int i = base + tid*8 + j;
    loc += (i < N) ? cnt[i] : 0;
  }
  sh[tid] = loc;
  __syncthreads();
  for(int off=128; off>0; off>>=1){
    if (tid < off) sh[tid] += sh[tid+off];
    __syncthreads();
  }
  if (tid == 0) bsum[blockIdx.x] = sh[0];
}
__global__ void k_scan2(int* __restrict__ bsum, int nb){
  if (threadIdx.x == 0){
    int run = 0;
    for(int i=0;i<nb;i++){ int t = bsum[i]; bsum[i] = run; run += t; }
  }
}
__global__ __launch_bounds__(256) void k_scan3(const int* __restrict__ cnt, const int* __restrict__ bsum,
                                               int* __restrict__ rowptr, int* __restrict__ cursor, int N){
  __shared__ int sh[256];
  int base = blockIdx.x*2048;
  int tid = threadIdx.x;
  int v[8]; int loc = 0;
  #pragma unroll
  for(int j=0;j<8;j++){
    int i = base + tid*8 + j;
    v[j] = (i < N) ? cnt[i] : 0;
    loc += v[j];
  }
  sh[tid] = loc;
  __syncthreads();
  for(int off=1; off<256; off<<=1){
    int add = (tid>=off) ? sh[tid-off] : 0;
    __syncthreads();
    sh[tid] += add;
    __syncthreads();
  }
  int run = ((tid==0) ? 0 : sh[tid-1]) + bsum[blockIdx.x];
  #pragma unroll
  for(int j=0;j<8;j++){
    int i = base + tid*8 + j;
    if (i < N){
      rowptr[i] = run; cursor[i] = run; run += v[j];
      if (i == N-1) rowptr[N] = run;
    }
  }
}

__global__ void k_fill(const int* __restrict__ src, const int* __restrict__ dst,
                       const float* __restrict__ ew, int E,
                       int* __restrict__ cursor, int* __restrict__ srcs,
                       float4* __restrict__ wq){
  int e = blockIdx.x*blockDim.x + threadIdx.x;
  if (e >= E) return;
  int d = dst[e];
  int pos = atomicAdd(&cursor[d], 1);
  srcs[pos] = src[e];
  wq[pos] = make_float4(ew[e], ew[(size_t)E + e], ew[2*(size_t)E + e], ew[3*(size_t)E + e]);
}

// ---------------- per-row bitonic sort of CSR segment by src (wave per row) ----------------
// Locality: sorted rows => all waves sweep the gather table front-to-back in unison.
__global__ __launch_bounds__(256) void k_sort(const int* __restrict__ rowptr,
                                              int* __restrict__ srcs, float4* __restrict__ wq, int N){
  int wid = (blockIdx.x*blockDim.x + threadIdx.x)>>6;
  int lane = threadIdx.x & 63;
  if (wid >= N) return;
  int p0 = rowptr[wid], p1 = rowptr[wid+1];
  int deg = p1 - p0;
  if (deg <= 1 || deg > 64) return;   // deg>64: P~0 for Poisson(32); leave unsorted (correct either way)
  int key = 0x7fffffc0 | lane;        // pad: src=max, keep lane in low bits
  float4 w = make_float4(0,0,0,0);
  if (lane < deg){
    key = (srcs[p0+lane] << 6) | lane;   // src < 65536 fits in 25 bits
    w = wq[p0+lane];
  }
  // bitonic sort 64 lanes, ascending by key
  #pragma unroll
  for (int k = 2; k <= 64; k <<= 1){
    #pragma unroll
    for (int j = k >> 1; j > 0; j >>= 1){
      int other = __shfl_xor(key, j, 64);
      bool up = ((lane & k) == 0);
      bool keepmin = (((lane & j) == 0) == up);
      key = keepmin ? min(key, other) : max(key, other);
    }
  }
  int owner = key & 63;
  float4 sw;
  sw.x = __shfl(w.x, owner, 64);
  sw.y = __shfl(w.y, owner, 64);
  sw.z = __shfl(w.z, owner, 64);
  sw.w = __shfl(w.w, owner, 64);
  if (lane < deg){
    srcs[p0+lane] = key >> 6;
    wq[p0+lane] = sw;
  }
}

// -------- MFMA bf16 GEMM (BM=64, BN=CT*16, K=128) + fused post_gemm epilogue --------
template<int CT>
__global__ __launch_bounds__(256) void k_gemm_fused(
    const bfraw* __restrict__ Abase, int lda, int abroff,
    const bfraw* __restrict__ Wb,          // [4][BN][128] bf16
    const float* __restrict__ nin, int nstride, int nbroff,
    const float* __restrict__ hball,       // [4][BN] f32
    bfraw* __restrict__ xt,                // [M][4][BN] bf16
    int M)
{
  constexpr int BN = CT*16;
  __shared__ bfraw tile[64*BN];
  int br = blockIdx.z;
  const bfraw* A = Abase + (size_t)br*abroff;
  const bfraw* W = Wb + (size_t)br*BN*128;
  const float* hb = hball + (size_t)br*BN;
  int rb = blockIdx.x*64;
  int t = threadIdx.x;
  int wave = t>>6, lane = t&63;
  int cl = lane&15, grp = lane>>4;

  int rowA = rb + wave*16 + cl;
  bf16x8 afr[4];
  bf16x8 zf = {0,0,0,0,0,0,0,0};
  #pragma unroll
  for(int ks=0;ks<4;ks++){
    if (rowA < M) afr[ks] = *(const bf16x8*)(A + (size_t)rowA*lda + ks*32 + grp*8);
    else          afr[ks] = zf;
  }
  f32x4 acc[CT];
  #pragma unroll
  for(int ct=0;ct<CT;ct++) acc[ct] = f32x4{0.f,0.f,0.f,0.f};
  #pragma unroll
  for(int ct=0;ct<CT;ct++){
    #pragma unroll
    for(int ks=0;ks<4;ks++){
      bf16x8 bfr = *(const bf16x8*)(W + (size_t)(ct*16+cl)*128 + ks*32 + grp*8);
      acc[ct] = __builtin_amdgcn_mfma_f32_16x16x32_bf16(afr[ks], bfr, acc[ct], 0,0,0);
    }
  }
  float hv[CT]; float hb2 = 0.f;
  #pragma unroll
  for(int ct=0;ct<CT;ct++){ hv[ct] = hb[cl+16*ct]; hb2 += hv[ct]*hv[ct]; }
  hb2 = gredw<16>(hb2);
  #pragma unroll
  for(int j=0;j<4;j++){
    int rloc = wave*16 + grp*4 + j;
    int node = rb + rloc;
    bool v = node < M;
    float m[CT]; float ss = 0.f;
    #pragma unroll
    for(int ct=0;ct<CT;ct++){ m[ct] = acc[ct][j]; ss += m[ct]*m[ct]; }
    ss = gredw<16>(ss);
    float mxn_raw = sqrtf(ss);
    float mxn = fmaxf(mxn_raw, 1e-15f);
    float xn = fmaxf(v ? nin[(size_t)node*nstride + br*nbroff] : 1.f, 1e-15f);
    float th = tanhf(mxn/xn * artanh_c(xn));
    float hs = (mxn_raw > 0.f) ? th/mxn : 0.f;
    float hn = (mxn_raw > 0.f) ? th : 0.f;
    if (hn > MAXN_P){ hs *= MAXN_P/hn; hn = MAXN_P; }
    float h[CT]; float xy = 0.f, x2 = 0.f;
    #pragma unroll
    for(int ct=0;ct<CT;ct++){ h[ct] = m[ct]*hs; xy += h[ct]*hv[ct]; x2 += h[ct]*h[ct]; }
    xy = gredw<16>(xy); x2 = gredw<16>(x2);
    float c1 = 1.f + 2.f*xy + hb2;
    float c2 = 1.f - x2;
    float den = fmaxf(1.f + 2.f*xy + x2*hb2, 1e-15f);
    float a[CT]; float as = 0.f;
    #pragma unroll
    for(int ct=0;ct<CT;ct++){ a[ct] = (c1*h[ct] + c2*hv[ct])/den; as += a[ct]*a[ct]; }
    as = gredw<16>(as);
    float an = fmaxf(sqrtf(as), 1e-15f);
    float s2 = 1.f;
    if (an > MAXN_P){ s2 = MAXN_P/an; an = MAXN_P; }
    float ls = artanh_c(an)/an * s2;
    #pragma unroll
    for(int ct=0;ct<CT;ct++) tile[rloc*BN + cl + 16*ct] = f2bf(a[ct]*ls);
  }
  __syncthreads();
  constexpr int IT = (64*BN)/(256*8);
  #pragma unroll
  for(int i=0;i<IT;i++){
    int flat = (t + i*256)*8;
    int row = flat/BN, col = flat%BN;
    int node = rb + row;
    if (node < M)
      *(uint4*)(xt + ((size_t)node*4 + br)*BN + col) = *(const uint4*)(tile + row*BN + col);
  }
}

// -------- fused 4-branch spmm layer0 (bf16 table, 1KB/row, depth-8, f32 weights) --------
__global__ __launch_bounds__(256) void k_spmm_l0(const int* __restrict__ rowptr,
                        const int* __restrict__ srcs, const float4* __restrict__ wq,
                        const bfraw* __restrict__ xt,
                        bfraw* __restrict__ hout, float* __restrict__ n4, int N){
  int wid = (blockIdx.x*blockDim.x + threadIdx.x)>>6;
  int lane = threadIdx.x & 63;
  if (wid >= N) return;
  int g = lane>>4;               // branch (16-lane groups, 8 dims/lane)
  float acc[8] = {0,0,0,0,0,0,0,0};
  int p0 = rowptr[wid], p1 = rowptr[wid+1];
  int p = p0;
  for (; p+8 <= p1; p += 8){
    int s[8]; float4 w[8]; uint4 u[8];
    #pragma unroll
    for(int i=0;i<8;i++){ s[i] = srcs[p+i]; w[i] = wq[p+i]; }
    #pragma unroll
    for(int i=0;i<8;i++) u[i] = *((const uint4*)(xt + (size_t)s[i]*512) + lane);
    #pragma unroll
    for(int i=0;i<8;i++) acc8(acc, sel4(w[i],g), u[i]);
  }
  for (; p+2 <= p1; p += 2){
    int s0 = srcs[p], s1 = srcs[p+1];
    float4 w0 = wq[p], w1 = wq[p+1];
    uint4 u0 = *((const uint4*)(xt + (size_t)s0*512) + lane);
    uint4 u1 = *((const uint4*)(xt + (size_t)s1*512) + lane);
    acc8(acc, sel4(w0,g), u0);
    acc8(acc, sel4(w1,g), u1);
  }
  if (p < p1){
    int s0 = srcs[p];
    float4 w0 = wq[p];
    uint4 u0 = *((const uint4*)(xt + (size_t)s0*512) + lane);
    acc8(acc, sel4(w0,g), u0);
  }
  float h[8];
  float qn = postK<16,8>(acc, h);
  uint4 o;
  o.x = (unsigned)f2bf(h[0]) | ((unsigned)f2bf(h[1])<<16);
  o.y = (unsigned)f2bf(h[2]) | ((unsigned)f2bf(h[3])<<16);
  o.z = (unsigned)f2bf(h[4]) | ((unsigned)f2bf(h[5])<<16);
  o.w = (unsigned)f2bf(h[6]) | ((unsigned)f2bf(h[7])<<16);
  *((uint4*)(hout + (size_t)wid*512) + lane) = o;
  if ((lane&15)==0) n4[(size_t)wid*4 + g] = qn;
}

// -------- fused 4-branch spmm layer1 (bf16, 512B/row, depth-8) + post + Mobius combine --------
__global__ __launch_bounds__(256) void k_spmm_l1(const int* __restrict__ rowptr,
                        const int* __restrict__ srcs, const float4* __restrict__ wq,
                        const bfraw* __restrict__ xt,
                        float* __restrict__ out, int N){
  int wid = (blockIdx.x*blockDim.x + threadIdx.x)>>6;
  int lane = threadIdx.x & 63;
  if (wid >= N) return;
  int g = lane>>4;               // branch (16-lane groups, 4 dims/lane)
  int slot = lane & 15;
  float acc[4] = {0,0,0,0};
  int p0 = rowptr[wid], p1 = rowptr[wid+1];
  int p = p0;
  for (; p+8 <= p1; p += 8){
    int s[8]; float4 w[8]; uint2 u[8];
    #pragma unroll
    for(int i=0;i<8;i++){ s[i] = srcs[p+i]; w[i] = wq[p+i]; }
    #pragma unroll
    for(int i=0;i<8;i++) u[i] = *((const uint2*)(xt + (size_t)s[i]*256) + lane);
    #pragma unroll
    for(int i=0;i<8;i++) acc4(acc, sel4(w[i],g), u[i]);
  }
  for (; p+2 <= p1; p += 2){
    int s0 = srcs[p], s1 = srcs[p+1];
    float4 w0 = wq[p], w1 = wq[p+1];
    uint2 u0 = *((const uint2*)(xt + (size_t)s0*256) + lane);
    uint2 u1 = *((const uint2*)(xt + (size_t)s1*256) + lane);
    acc4(acc, sel4(w0,g), u0);
    acc4(acc, sel4(w1,g), u1);
  }
  if (p < p1){
    int s0 = srcs[p];
    float4 w0 = wq[p];
    uint2 u0 = *((const uint2*)(xt + (size_t)s0*256) + lane);
    acc4(acc, sel4(w0,g), u0);
  }
  float hv[4];
  float qn = postK<16,4>(acc, hv);
  float xk[4][4]; float qk[4];
  #pragma unroll
  for(int k=0;k<4;k++){
    #pragma unroll
    for(int j=0;j<4;j++) xk[k][j] = __shfl(hv[j], slot + 16*k, 64);
    qk[k] = __shfl(qn, 16*k, 64);
  }
  float xn0 = fmaxf(qk[0], 1e-15f);
  float s0 = tanhf(0.125f*artanh_c(xn0))/xn0;
  float t[4] = {s0*xk[0][0], s0*xk[0][1], s0*xk[0][2], s0*xk[0][3]};
  #pragma unroll
  for(int k=1;k<4;k++){
    float yn = fmaxf(qk[k], 1e-15f);
    float sy = tanhf(0.125f*artanh_c(yn))/yn;
    float y[4] = {sy*xk[k][0], sy*xk[k][1], sy*xk[k][2], sy*xk[k][3]};
    float dx=0.f, dy=0.f, dxy=0.f;
    #pragma unroll
    for(int j=0;j<4;j++){ dx += t[j]*t[j]; dy += y[j]*y[j]; dxy += t[j]*y[j]; }
    float x2 = gredw<16>(dx);
    float y2 = gredw<16>(dy);
    float xy = gredw<16>(dxy);
    float c1 = 1.f + 2.f*xy + y2;
    float c2 = 1.f - x2;
    float den = fmaxf(1.f + 2.f*xy + x2*y2, 1e-15f);
    #pragma unroll
    for(int j=0;j<4;j++) t[j] = (c1*t[j] + c2*y[j])/den;
  }
  float s[4] = {0,0,0,0};
  #pragma unroll
  for(int k=0;k<4;k++){
    float nk = fmaxf(qk[k], 1e-15f);
    float lk = artanh_c(nk)/nk;
    #pragma unroll
    for(int j=0;j<4;j++) s[j] = fmaf(lk, xk[k][j], s[j]);
  }
  float dt = 0.f;
  #pragma unroll
  for(int j=0;j<4;j++) dt += t[j]*t[j];
  float tn = fmaxf(sqrtf(gredw<16>(dt)), 1e-15f);
  float lt = artanh_c(tn)/tn;
  #pragma unroll
  for(int j=0;j<4;j++) s[j] = 0.2f*fmaf(lt, t[j], s[j]);
  float ds = 0.f;
  #pragma unroll
  for(int j=0;j<4;j++) ds += s[j]*s[j];
  float an = fmaxf(sqrtf(gredw<16>(ds)), 1e-15f);
  float on = tanhf(an);
  float osc = on/an;
  if (on > MAXN_P) osc *= MAXN_P/on;
  if (g == 0)
    *(float4*)(out + (size_t)wid*64 + 4*slot) =
      make_float4(s[0]*osc, s[1]*osc, s[2]*osc, s[3]*osc);
}

extern "C" void kernel_launch(void* const* d_in, const int* in_sizes, int n_in,
                              void* d_out, int out_size, void* d_ws, size_t ws_size,
                              hipStream_t stream){
  const float* x   = (const float*)d_in[0];
  const int*   src = (const int*)d_in[1];
  const int*   dst = (const int*)d_in[2];
  const float* ew  = (const float*)d_in[3];   // [4,E]
  const float* W0  = (const float*)d_in[4];   // [4,HID,128]
  const float* b0  = (const float*)d_in[5];   // [4,HID]
  const float* W1  = (const float*)d_in[6];   // [4,DIM,HID]
  const float* b1  = (const float*)d_in[7];   // [4,DIM]
  float* out = (float*)d_out;

  const int FIN = 128;
  int N = in_sizes[0]/FIN;
  int E = in_sizes[1];
  int HID = in_sizes[5]/4;   // 128
  int DIM = in_sizes[7]/4;   // 64

  char* ws = (char*)d_ws;
  size_t off = 0;
  auto alloc = [&](size_t bytes)->char*{
    char* p = ws + off;
    off += (bytes + 255) & ~(size_t)255;
    return p;
  };
  bfraw* h4b    = (bfraw*)alloc((size_t)N*4*FIN*2);   // h4 bf16; prefix aliased as h0 bf16
  bfraw* xtb    = (bfraw*)alloc((size_t)N*4*FIN*2);   // bf16 gather tables (l0 full, l1 half)
  float* n0     = (float*)alloc((size_t)N*4);
  float* n4     = (float*)alloc((size_t)N*16);
  int*   rowptr = (int*)alloc((size_t)(N+1)*4);
  int*   cnt    = (int*)alloc((size_t)N*4);
  int*   cursor = (int*)alloc((size_t)N*4);
  int*   srcs   = (int*)alloc((size_t)E*4);
  float4* wq    = (float4*)alloc((size_t)E*16);
  float* hb0    = (float*)alloc((size_t)4*HID*4);
  float* hb1    = (float*)alloc((size_t)4*DIM*4);
  bfraw* w0b    = (bfraw*)alloc((size_t)4*HID*FIN*2);
  bfraw* w1b    = (bfraw*)alloc((size_t)4*DIM*HID*2);
  int*   bsum   = (int*)alloc((size_t)256*4);
  (void)ws_size; (void)n_in; (void)out_size;

  bfraw* h0 = h4b;   // h0 dead (after GEMM0) before spmm_l0 writes h4b

  int rowBlocks = (N + 3)/4;       // wave per node
  int nW0 = 4*HID*FIN, nW1 = 4*DIM*HID;
  int RB = rowBlocks;
  int HIST = (E + 255)/256;
  int W0B = (nW0 + 255)/256;
  int W1B = (nW1 + 255)/256;
  int nscan = (N + 2047)/2048;

  // fused prologue (exp0 | hist | w2bf x2 | hb), after cnt memset
  hipMemsetAsync(cnt, 0, (size_t)N*4, stream);
  k_prologue<<<RB + HIST + W0B + W1B + 8, 256, 0, stream>>>(
      x, h0, n0, N, dst, cnt, E, W0, w0b, nW0, W1, w1b, nW1,
      b0, b1, hb0, hb1, HID, DIM, RB, HIST, W0B, W1B);

  // hierarchical scan -> rowptr/cursor, CSR fill, then per-row src-sort (L2 locality)
  k_scan1<<<nscan, 256, 0, stream>>>(cnt, bsum, N);
  k_scan2<<<1, 64, 0, stream>>>(bsum, nscan);
  k_scan3<<<nscan, 256, 0, stream>>>(cnt, bsum, rowptr, cursor, N);
  k_fill<<<HIST, 256, 0, stream>>>(src, dst, ew, E, cursor, srcs, wq);
  k_sort<<<rowBlocks, 256, 0, stream>>>(rowptr, srcs, wq, N);

  // layer 0: MFMA GEMM + fused post (bf16 xt out) -> fused spmm(+post, bf16 out)
  k_gemm_fused<8><<<dim3((N+63)/64, 1, 4), 256, 0, stream>>>(
      h0, FIN, 0, w0b, n0, 1, 0, hb0, xtb, N);
  k_spmm_l0<<<rowBlocks, 256, 0, stream>>>(rowptr, srcs, wq, xtb, h4b, n4, N);

  // layer 1: MFMA GEMM + fused post (bf16 xt out) -> fused spmm(+post+combine) -> out
  k_gemm_fused<4><<<dim3((N+63)/64, 1, 4), 256, 0, stream>>>(
      h4b, 4*HID, HID, w1b, n4, 4, 1, hb1, xtb, N);
  k_spmm_l1<<<rowBlocks, 256, 0, stream>>>(rowptr, srcs, wq, xtb, out, N);
}

// Round 11
// 677.007 us; speedup vs baseline: 1.0761x; 1.0761x over previous
//
#include <hip/hip_runtime.h>
#include <math.h>

#define MAXN_P 0.996f   // (1 - PROJ_EPS)/sqrt(c), c=1

typedef unsigned short bfraw;
typedef __attribute__((ext_vector_type(8))) short bf16x8;
typedef __attribute__((ext_vector_type(4))) float f32x4;

__device__ __forceinline__ float wred(float v){
  #pragma unroll
  for(int o=32;o>0;o>>=1) v += __shfl_xor(v,o,64);
  return v;
}
template<int W>
__device__ __forceinline__ float gredw(float v){
  #pragma unroll
  for(int o=W/2;o>0;o>>=1) v += __shfl_xor(v,o,64);
  return v;
}
__device__ __forceinline__ float artanh_c(float x){
  x = fminf(fmaxf(x, -1.0f+1e-7f), 1.0f-1e-7f);
  return atanhf(x);
}
__device__ __forceinline__ float sel4(float4 w, int g){
  float ab = (g&1) ? w.y : w.x;
  float cd = (g&1) ? w.w : w.z;
  return (g&2) ? cd : ab;
}
__device__ __forceinline__ bfraw f2bf(float f){
  unsigned u = __float_as_uint(f);
  unsigned r = (u + 0x7fffu + ((u>>16)&1u)) >> 16;   // RNE
  return (bfraw)r;
}
__device__ __forceinline__ float bflo(unsigned u){ return __uint_as_float(u<<16); }
__device__ __forceinline__ float bfhi(unsigned u){ return __uint_as_float(u & 0xffff0000u); }

__device__ __forceinline__ void acc8(float* a, float w, uint4 u){
  a[0]=fmaf(w, bflo(u.x), a[0]); a[1]=fmaf(w, bfhi(u.x), a[1]);
  a[2]=fmaf(w, bflo(u.y), a[2]); a[3]=fmaf(w, bfhi(u.y), a[3]);
  a[4]=fmaf(w, bflo(u.z), a[4]); a[5]=fmaf(w, bfhi(u.z), a[5]);
  a[6]=fmaf(w, bflo(u.w), a[6]); a[7]=fmaf(w, bfhi(u.w), a[7]);
}

// post_spmm chain: u -> proj(expmap0(u)) -> relu(logmap0) -> proj(expmap0); norms over W lanes
template<int W, int K>
__device__ __forceinline__ float postK(const float* u, float* h){
  float ss = 0.f;
  #pragma unroll
  for(int k=0;k<K;k++) ss += u[k]*u[k];
  ss = gredw<W>(ss);
  float un = fmaxf(sqrtf(ss), 1e-15f);
  float t1 = tanhf(un);
  float sc = t1/un;
  float pn = t1;
  if (pn > MAXN_P){ sc *= MAXN_P/pn; pn = MAXN_P; }
  float ln = fmaxf(pn, 1e-15f);
  float m = sc * (artanh_c(ln)/ln);
  float v[K]; float vs = 0.f;
  #pragma unroll
  for(int k=0;k<K;k++){ v[k] = fmaxf(u[k]*m, 0.f); vs += v[k]*v[k]; }
  vs = gredw<W>(vs);
  float vn = fmaxf(sqrtf(vs), 1e-15f);
  float t2 = tanhf(vn);
  float qs = t2/vn;
  float qn = t2;
  if (qn > MAXN_P){ qs *= MAXN_P/qn; qn = MAXN_P; }
  #pragma unroll
  for(int k=0;k<K;k++) h[k] = v[k]*qs;
  return qn;
}

// ---------------- fused prologue: exp0 | hist | w2bf(W0) | w2bf(W1) | hb ----------------
__global__ __launch_bounds__(256) void k_prologue(
    const float* __restrict__ x, bfraw* __restrict__ h0, float* __restrict__ n0, int N,
    const int* __restrict__ dst, int* __restrict__ cnt, int E,
    const float* __restrict__ W0, bfraw* __restrict__ w0b, int nW0,
    const float* __restrict__ W1, bfraw* __restrict__ w1b, int nW1,
    const float* __restrict__ b0, const float* __restrict__ b1,
    float* __restrict__ hb0, float* __restrict__ hb1, int HID, int DIM,
    int RB, int HIST, int W0B, int W1B)
{
  int b = blockIdx.x;
  int tid = threadIdx.x;
  if (b < RB){
    int wid = (b*256 + tid)>>6;
    int lane = tid & 63;
    if (wid >= N) return;
    const float* r = x + (size_t)wid*128;
    float u0 = r[lane], u1 = r[lane+64];
    float ss = wred(u0*u0 + u1*u1);
    float un = fmaxf(sqrtf(ss), 1e-15f);
    float tn = tanhf(un);
    float sc = tn/un;
    float pn = tn;
    if (pn > MAXN_P){ sc *= MAXN_P/pn; pn = MAXN_P; }
    h0[(size_t)wid*128 + lane]      = f2bf(u0*sc);
    h0[(size_t)wid*128 + lane + 64] = f2bf(u1*sc);
    if (lane == 0) n0[wid] = pn;
    return;
  }
  b -= RB;
  if (b < HIST){
    int e = b*256 + tid;
    if (e < E) atomicAdd(&cnt[dst[e]], 1);
    return;
  }
  b -= HIST;
  if (b < W0B){
    int i = b*256 + tid;
    if (i < nW0) w0b[i] = f2bf(W0[i]);
    return;
  }
  b -= W0B;
  if (b < W1B){
    int i = b*256 + tid;
    if (i < nW1) w1b[i] = f2bf(W1[i]);
    return;
  }
  b -= W1B;
  {
    if (tid >= 64) return;
    int layer = b >> 2, br = b & 3;
    int D = layer ? DIM : HID;
    const float* bb = layer ? (b1 + (size_t)br*DIM) : (b0 + (size_t)br*HID);
    float* o        = layer ? (hb1 + (size_t)br*DIM) : (hb0 + (size_t)br*HID);
    float v0 = (tid < D) ? bb[tid] : 0.f;
    float v1 = (tid+64 < D) ? bb[tid+64] : 0.f;
    float ss = wred(v0*v0 + v1*v1);
    float n = fmaxf(sqrtf(ss), 1e-15f);
    float tn = tanhf(n);
    float sc = tn/n;
    if (tn > MAXN_P) sc *= MAXN_P/tn;
    if (tid < D)    o[tid]    = v0*sc;
    if (tid+64 < D) o[tid+64] = v1*sc;
  }
}

// ---------------- hierarchical scan: cnt[N] -> rowptr[N+1], cursor[N] ----------------
__global__ __launch_bounds__(256) void k_scan1(const int* __restrict__ cnt, int* __restrict__ bsum, int N){
  __shared__ int sh[256];
  int base = blockIdx.x*2048;
  int tid = threadIdx.x;
  int loc = 0;
  #pragma unroll
  for(int j=0;j<8;j++){
    int i = base + tid*8 + j;
    loc += (i < N) ? cnt[i] : 0;
  }
  sh[tid] = loc;
  __syncthreads();
  for(int off=128; off>0; off>>=1){
    if (tid < off) sh[tid] += sh[tid+off];
    __syncthreads();
  }
  if (tid == 0) bsum[blockIdx.x] = sh[0];
}
__global__ void k_scan2(int* __restrict__ bsum, int nb){
  if (threadIdx.x == 0){
    int run = 0;
    for(int i=0;i<nb;i++){ int t = bsum[i]; bsum[i] = run; run += t; }
  }
}
__global__ __launch_bounds__(256) void k_scan3(const int* __restrict__ cnt, const int* __restrict__ bsum,
                                               int* __restrict__ rowptr, int* __restrict__ cursor, int N){
  __shared__ int sh[256];
  int base = blockIdx.x*2048;
  int tid = threadIdx.x;
  int v[8]; int loc = 0;
  #pragma unroll
  for(int j=0;j<8;j++){
    int i = base + tid*8 + j;
    v[j] = (i < N) ? cnt[i] : 0;
    loc += v[j];
  }
  sh[tid] = loc;
  __syncthreads();
  for(int off=1; off<256; off<<=1){
    int add = (tid>=off) ? sh[tid-off] : 0;
    __syncthreads();
    sh[tid] += add;
    __syncthreads();
  }
  int run = ((tid==0) ? 0 : sh[tid-1]) + bsum[blockIdx.x];
  #pragma unroll
  for(int j=0;j<8;j++){
    int i = base + tid*8 + j;
    if (i < N){
      rowptr[i] = run; cursor[i] = run; run += v[j];
      if (i == N-1) rowptr[N] = run;
    }
  }
}

__global__ void k_fill(const int* __restrict__ src, const int* __restrict__ dst,
                       const float* __restrict__ ew, int E,
                       int* __restrict__ cursor, int* __restrict__ srcs,
                       float4* __restrict__ wq){
  int e = blockIdx.x*blockDim.x + threadIdx.x;
  if (e >= E) return;
  int d = dst[e];
  int pos = atomicAdd(&cursor[d], 1);
  srcs[pos] = src[e];
  wq[pos] = make_float4(ew[e], ew[(size_t)E + e], ew[2*(size_t)E + e], ew[3*(size_t)E + e]);
}

// -------- MFMA bf16 GEMM (BM=64, BN=CT*16, K=128) + fused post_gemm epilogue --------
template<int CT>
__global__ __launch_bounds__(256) void k_gemm_fused(
    const bfraw* __restrict__ Abase, int lda, int abroff,
    const bfraw* __restrict__ Wb,          // [4][BN][128] bf16
    const float* __restrict__ nin, int nstride, int nbroff,
    const float* __restrict__ hball,       // [4][BN] f32
    bfraw* __restrict__ xt,                // [M][4][BN] bf16
    int M)
{
  constexpr int BN = CT*16;
  __shared__ bfraw tile[64*BN];
  int br = blockIdx.z;
  const bfraw* A = Abase + (size_t)br*abroff;
  const bfraw* W = Wb + (size_t)br*BN*128;
  const float* hb = hball + (size_t)br*BN;
  int rb = blockIdx.x*64;
  int t = threadIdx.x;
  int wave = t>>6, lane = t&63;
  int cl = lane&15, grp = lane>>4;

  int rowA = rb + wave*16 + cl;
  bf16x8 afr[4];
  bf16x8 zf = {0,0,0,0,0,0,0,0};
  #pragma unroll
  for(int ks=0;ks<4;ks++){
    if (rowA < M) afr[ks] = *(const bf16x8*)(A + (size_t)rowA*lda + ks*32 + grp*8);
    else          afr[ks] = zf;
  }
  f32x4 acc[CT];
  #pragma unroll
  for(int ct=0;ct<CT;ct++) acc[ct] = f32x4{0.f,0.f,0.f,0.f};
  #pragma unroll
  for(int ct=0;ct<CT;ct++){
    #pragma unroll
    for(int ks=0;ks<4;ks++){
      bf16x8 bfr = *(const bf16x8*)(W + (size_t)(ct*16+cl)*128 + ks*32 + grp*8);
      acc[ct] = __builtin_amdgcn_mfma_f32_16x16x32_bf16(afr[ks], bfr, acc[ct], 0,0,0);
    }
  }
  float hv[CT]; float hb2 = 0.f;
  #pragma unroll
  for(int ct=0;ct<CT;ct++){ hv[ct] = hb[cl+16*ct]; hb2 += hv[ct]*hv[ct]; }
  hb2 = gredw<16>(hb2);
  #pragma unroll
  for(int j=0;j<4;j++){
    int rloc = wave*16 + grp*4 + j;
    int node = rb + rloc;
    bool v = node < M;
    float m[CT]; float ss = 0.f;
    #pragma unroll
    for(int ct=0;ct<CT;ct++){ m[ct] = acc[ct][j]; ss += m[ct]*m[ct]; }
    ss = gredw<16>(ss);
    float mxn_raw = sqrtf(ss);
    float mxn = fmaxf(mxn_raw, 1e-15f);
    float xn = fmaxf(v ? nin[(size_t)node*nstride + br*nbroff] : 1.f, 1e-15f);
    float th = tanhf(mxn/xn * artanh_c(xn));
    float hs = (mxn_raw > 0.f) ? th/mxn : 0.f;
    float hn = (mxn_raw > 0.f) ? th : 0.f;
    if (hn > MAXN_P){ hs *= MAXN_P/hn; hn = MAXN_P; }
    float h[CT]; float xy = 0.f, x2 = 0.f;
    #pragma unroll
    for(int ct=0;ct<CT;ct++){ h[ct] = m[ct]*hs; xy += h[ct]*hv[ct]; x2 += h[ct]*h[ct]; }
    xy = gredw<16>(xy); x2 = gredw<16>(x2);
    float c1 = 1.f + 2.f*xy + hb2;
    float c2 = 1.f - x2;
    float den = fmaxf(1.f + 2.f*xy + x2*hb2, 1e-15f);
    float a[CT]; float as = 0.f;
    #pragma unroll
    for(int ct=0;ct<CT;ct++){ a[ct] = (c1*h[ct] + c2*hv[ct])/den; as += a[ct]*a[ct]; }
    as = gredw<16>(as);
    float an = fmaxf(sqrtf(as), 1e-15f);
    float s2 = 1.f;
    if (an > MAXN_P){ s2 = MAXN_P/an; an = MAXN_P; }
    float ls = artanh_c(an)/an * s2;
    #pragma unroll
    for(int ct=0;ct<CT;ct++) tile[rloc*BN + cl + 16*ct] = f2bf(a[ct]*ls);
  }
  __syncthreads();
  constexpr int IT = (64*BN)/(256*8);
  #pragma unroll
  for(int i=0;i<IT;i++){
    int flat = (t + i*256)*8;
    int row = flat/BN, col = flat%BN;
    int node = rb + row;
    if (node < M)
      *(uint4*)(xt + ((size_t)node*4 + br)*BN + col) = *(const uint4*)(tile + row*BN + col);
  }
}

// -------- fused 4-branch spmm layer0 (bf16 table, 1KB/row, depth-8, f32 weights) --------
__global__ __launch_bounds__(256) void k_spmm_l0(const int* __restrict__ rowptr,
                        const int* __restrict__ srcs, const float4* __restrict__ wq,
                        const bfraw* __restrict__ xt,
                        bfraw* __restrict__ hout, float* __restrict__ n4, int N){
  int wid = (blockIdx.x*blockDim.x + threadIdx.x)>>6;
  int lane = threadIdx.x & 63;
  if (wid >= N) return;
  int g = lane>>4;               // branch (16-lane groups, 8 dims/lane)
  float acc[8] = {0,0,0,0,0,0,0,0};
  int p0 = rowptr[wid], p1 = rowptr[wid+1];
  int p = p0;
  for (; p+8 <= p1; p += 8){
    int s[8]; float4 w[8]; uint4 u[8];
    #pragma unroll
    for(int i=0;i<8;i++){ s[i] = srcs[p+i]; w[i] = wq[p+i]; }
    #pragma unroll
    for(int i=0;i<8;i++) u[i] = *((const uint4*)(xt + (size_t)s[i]*512) + lane);
    #pragma unroll
    for(int i=0;i<8;i++) acc8(acc, sel4(w[i],g), u[i]);
  }
  for (; p+2 <= p1; p += 2){
    int s0 = srcs[p], s1 = srcs[p+1];
    float4 w0 = wq[p], w1 = wq[p+1];
    uint4 u0 = *((const uint4*)(xt + (size_t)s0*512) + lane);
    uint4 u1 = *((const uint4*)(xt + (size_t)s1*512) + lane);
    acc8(acc, sel4(w0,g), u0);
    acc8(acc, sel4(w1,g), u1);
  }
  if (p < p1){
    int s0 = srcs[p];
    float4 w0 = wq[p];
    uint4 u0 = *((const uint4*)(xt + (size_t)s0*512) + lane);
    acc8(acc, sel4(w0,g), u0);
  }
  float h[8];
  float qn = postK<16,8>(acc, h);
  uint4 o;
  o.x = (unsigned)f2bf(h[0]) | ((unsigned)f2bf(h[1])<<16);
  o.y = (unsigned)f2bf(h[2]) | ((unsigned)f2bf(h[3])<<16);
  o.z = (unsigned)f2bf(h[4]) | ((unsigned)f2bf(h[5])<<16);
  o.w = (unsigned)f2bf(h[6]) | ((unsigned)f2bf(h[7])<<16);
  *((uint4*)(hout + (size_t)wid*512) + lane) = o;
  if ((lane&15)==0) n4[(size_t)wid*4 + g] = qn;
}

// -------- fused 4-branch spmm layer1: TWO dst rows per wave (uint4/lane = 2x512B rows
// per load step), depth-4 guarded loop + post + Mobius combine --------
__global__ __launch_bounds__(256) void k_spmm_l1(const int* __restrict__ rowptr,
                        const int* __restrict__ srcs, const float4* __restrict__ wq,
                        const bfraw* __restrict__ xt,
                        float* __restrict__ out, int N){
  int wpair = (blockIdx.x*blockDim.x + threadIdx.x)>>6;
  int lane = threadIdx.x & 63;
  int half = lane>>5;            // 0: row 2w, 1: row 2w+1
  int l31 = lane & 31;
  int row = wpair*2 + half;
  bool rv = row < N;
  int rc = rv ? row : 0;
  int p0 = rowptr[rc];
  int p1 = rv ? rowptr[rc+1] : p0;
  // wave-uniform max degree
  int deg = p1 - p0;
  int mx = deg;
  #pragma unroll
  for(int o=32;o>0;o>>=1) mx = max(mx, __shfl_xor(mx, o, 64));
  int g = l31 >> 3;              // branch (8-lane groups, 8 dims/lane)
  int slot = l31 & 7;
  float acc[8] = {0,0,0,0,0,0,0,0};
  for (int i = 0; i < mx; i += 4){
    int pe[4]; float wv[4]; uint4 u[4];
    #pragma unroll
    for(int j=0;j<4;j++){
      int pi = p0 + i + j;
      bool v = pi < p1;
      pe[j] = v ? pi : 0;
      wv[j] = v ? 1.f : 0.f;
    }
    int s[4]; float4 w4[4];
    #pragma unroll
    for(int j=0;j<4;j++){ s[j] = srcs[pe[j]]; w4[j] = wq[pe[j]]; }
    #pragma unroll
    for(int j=0;j<4;j++) u[j] = *((const uint4*)(xt + (size_t)s[j]*256) + l31);
    #pragma unroll
    for(int j=0;j<4;j++) acc8(acc, wv[j]*sel4(w4[j],g), u[j]);
  }
  // per-branch post_spmm chain (norms across 8-lane groups)
  float h[8];
  float qn = postK<8,8>(acc, h);
  // cross-branch combine within each 32-lane half
  int hb = half*32;
  float t[8], s[8];
  float qk0 = fmaxf(__shfl(qn, hb + 0, 64), 1e-15f);
  float lk0 = artanh_c(qk0)/qk0;
  float s0 = tanhf(0.125f*artanh_c(qk0))/qk0;
  #pragma unroll
  for(int j=0;j<8;j++){
    float xv = __shfl(h[j], hb + slot, 64);   // branch 0
    t[j] = s0*xv;
    s[j] = lk0*xv;
  }
  #pragma unroll
  for(int k=1;k<4;k++){
    float qk = fmaxf(__shfl(qn, hb + k*8, 64), 1e-15f);
    float lk = artanh_c(qk)/qk;
    float sy = tanhf(0.125f*artanh_c(qk))/qk;
    float y[8];
    float dx=0.f, dy=0.f, dxy=0.f;
    #pragma unroll
    for(int j=0;j<8;j++){
      float xv = __shfl(h[j], hb + k*8 + slot, 64);
      y[j] = sy*xv;
      s[j] = fmaf(lk, xv, s[j]);
      dx += t[j]*t[j]; dy += y[j]*y[j]; dxy += t[j]*y[j];
    }
    float x2 = gredw<8>(dx);
    float y2 = gredw<8>(dy);
    float xy = gredw<8>(dxy);
    float c1 = 1.f + 2.f*xy + y2;
    float c2 = 1.f - x2;
    float den = fmaxf(1.f + 2.f*xy + x2*y2, 1e-15f);
    #pragma unroll
    for(int j=0;j<8;j++) t[j] = (c1*t[j] + c2*y[j])/den;
  }
  float dt = 0.f;
  #pragma unroll
  for(int j=0;j<8;j++) dt += t[j]*t[j];
  float tn = fmaxf(sqrtf(gredw<8>(dt)), 1e-15f);
  float lt = artanh_c(tn)/tn;
  #pragma unroll
  for(int j=0;j<8;j++) s[j] = 0.2f*fmaf(lt, t[j], s[j]);
  float ds = 0.f;
  #pragma unroll
  for(int j=0;j<8;j++) ds += s[j]*s[j];
  float an = fmaxf(sqrtf(gredw<8>(ds)), 1e-15f);
  float on = tanhf(an);
  float osc = on/an;
  if (on > MAXN_P) osc *= MAXN_P/on;
  if (g == 0 && rv){   // 8 lanes per half x 8 dims = 64
    float* orow = out + (size_t)row*64 + slot*8;
    *(float4*)(orow)     = make_float4(s[0]*osc, s[1]*osc, s[2]*osc, s[3]*osc);
    *(float4*)(orow + 4) = make_float4(s[4]*osc, s[5]*osc, s[6]*osc, s[7]*osc);
  }
}

extern "C" void kernel_launch(void* const* d_in, const int* in_sizes, int n_in,
                              void* d_out, int out_size, void* d_ws, size_t ws_size,
                              hipStream_t stream){
  const float* x   = (const float*)d_in[0];
  const int*   src = (const int*)d_in[1];
  const int*   dst = (const int*)d_in[2];
  const float* ew  = (const float*)d_in[3];   // [4,E]
  const float* W0  = (const float*)d_in[4];   // [4,HID,128]
  const float* b0  = (const float*)d_in[5];   // [4,HID]
  const float* W1  = (const float*)d_in[6];   // [4,DIM,HID]
  const float* b1  = (const float*)d_in[7];   // [4,DIM]
  float* out = (float*)d_out;

  const int FIN = 128;
  int N = in_sizes[0]/FIN;
  int E = in_sizes[1];
  int HID = in_sizes[5]/4;   // 128
  int DIM = in_sizes[7]/4;   // 64

  char* ws = (char*)d_ws;
  size_t off = 0;
  auto alloc = [&](size_t bytes)->char*{
    char* p = ws + off;
    off += (bytes + 255) & ~(size_t)255;
    return p;
  };
  bfraw* h4b    = (bfraw*)alloc((size_t)N*4*FIN*2);   // h4 bf16; prefix aliased as h0 bf16
  bfraw* xtb    = (bfraw*)alloc((size_t)N*4*FIN*2);   // bf16 gather tables (l0 full, l1 half)
  float* n0     = (float*)alloc((size_t)N*4);
  float* n4     = (float*)alloc((size_t)N*16);
  int*   rowptr = (int*)alloc((size_t)(N+1)*4);
  int*   cnt    = (int*)alloc((size_t)N*4);
  int*   cursor = (int*)alloc((size_t)N*4);
  int*   srcs   = (int*)alloc((size_t)E*4);
  float4* wq    = (float4*)alloc((size_t)E*16);
  float* hb0    = (float*)alloc((size_t)4*HID*4);
  float* hb1    = (float*)alloc((size_t)4*DIM*4);
  bfraw* w0b    = (bfraw*)alloc((size_t)4*HID*FIN*2);
  bfraw* w1b    = (bfraw*)alloc((size_t)4*DIM*HID*2);
  int*   bsum   = (int*)alloc((size_t)256*4);
  (void)ws_size; (void)n_in; (void)out_size;

  bfraw* h0 = h4b;   // h0 dead (after GEMM0) before spmm_l0 writes h4b

  int rowBlocks = (N + 3)/4;       // wave per node
  int pairBlocks = (N + 7)/8;      // wave per 2 nodes (spmm_l1)
  int nW0 = 4*HID*FIN, nW1 = 4*DIM*HID;
  int RB = rowBlocks;
  int HIST = (E + 255)/256;
  int W0B = (nW0 + 255)/256;
  int W1B = (nW1 + 255)/256;
  int nscan = (N + 2047)/2048;

  // fused prologue (exp0 | hist | w2bf x2 | hb), after cnt memset
  hipMemsetAsync(cnt, 0, (size_t)N*4, stream);
  k_prologue<<<RB + HIST + W0B + W1B + 8, 256, 0, stream>>>(
      x, h0, n0, N, dst, cnt, E, W0, w0b, nW0, W1, w1b, nW1,
      b0, b1, hb0, hb1, HID, DIM, RB, HIST, W0B, W1B);

  // hierarchical scan -> rowptr/cursor, then CSR fill (f32 weights)
  k_scan1<<<nscan, 256, 0, stream>>>(cnt, bsum, N);
  k_scan2<<<1, 64, 0, stream>>>(bsum, nscan);
  k_scan3<<<nscan, 256, 0, stream>>>(cnt, bsum, rowptr, cursor, N);
  k_fill<<<HIST, 256, 0, stream>>>(src, dst, ew, E, cursor, srcs, wq);

  // layer 0: MFMA GEMM + fused post (bf16 xt out) -> fused spmm(+post, bf16 out)
  k_gemm_fused<8><<<dim3((N+63)/64, 1, 4), 256, 0, stream>>>(
      h0, FIN, 0, w0b, n0, 1, 0, hb0, xtb, N);
  k_spmm_l0<<<rowBlocks, 256, 0, stream>>>(rowptr, srcs, wq, xtb, h4b, n4, N);

  // layer 1: MFMA GEMM + fused post (bf16 xt out) -> fused spmm(+post+combine, 2 rows/wave) -> out
  k_gemm_fused<4><<<dim3((N+63)/64, 1, 4), 256, 0, stream>>>(
      h4b, 4*HID, HID, w1b, n4, 4, 1, hb1, xtb, N);
  k_spmm_l1<<<pairBlocks, 256, 0, stream>>>(rowptr, srcs, wq, xtb, out, N);
}

// Round 12
// 675.239 us; speedup vs baseline: 1.0789x; 1.0026x over previous
//
#include <hip/hip_runtime.h>
#include <math.h>

#define MAXN_P 0.996f   // (1 - PROJ_EPS)/sqrt(c), c=1

typedef unsigned short bfraw;
typedef __attribute__((ext_vector_type(8))) short bf16x8;
typedef __attribute__((ext_vector_type(4))) float f32x4;

__device__ __forceinline__ float wred(float v){
  #pragma unroll
  for(int o=32;o>0;o>>=1) v += __shfl_xor(v,o,64);
  return v;
}
template<int W>
__device__ __forceinline__ float gredw(float v){
  #pragma unroll
  for(int o=W/2;o>0;o>>=1) v += __shfl_xor(v,o,64);
  return v;
}
__device__ __forceinline__ float artanh_c(float x){
  x = fminf(fmaxf(x, -1.0f+1e-7f), 1.0f-1e-7f);
  return atanhf(x);
}
__device__ __forceinline__ float sel4(float4 w, int g){
  float ab = (g&1) ? w.y : w.x;
  float cd = (g&1) ? w.w : w.z;
  return (g&2) ? cd : ab;
}
__device__ __forceinline__ bfraw f2bf(float f){
  unsigned u = __float_as_uint(f);
  unsigned r = (u + 0x7fffu + ((u>>16)&1u)) >> 16;   // RNE
  return (bfraw)r;
}
__device__ __forceinline__ float bflo(unsigned u){ return __uint_as_float(u<<16); }
__device__ __forceinline__ float bfhi(unsigned u){ return __uint_as_float(u & 0xffff0000u); }

__device__ __forceinline__ void acc8(float* a, float w, uint4 u){
  a[0]=fmaf(w, bflo(u.x), a[0]); a[1]=fmaf(w, bfhi(u.x), a[1]);
  a[2]=fmaf(w, bflo(u.y), a[2]); a[3]=fmaf(w, bfhi(u.y), a[3]);
  a[4]=fmaf(w, bflo(u.z), a[4]); a[5]=fmaf(w, bfhi(u.z), a[5]);
  a[6]=fmaf(w, bflo(u.w), a[6]); a[7]=fmaf(w, bfhi(u.w), a[7]);
}

// post_spmm chain: u -> proj(expmap0(u)) -> relu(logmap0) -> proj(expmap0); norms over W lanes
template<int W, int K>
__device__ __forceinline__ float postK(const float* u, float* h){
  float ss = 0.f;
  #pragma unroll
  for(int k=0;k<K;k++) ss += u[k]*u[k];
  ss = gredw<W>(ss);
  float un = fmaxf(sqrtf(ss), 1e-15f);
  float t1 = tanhf(un);
  float sc = t1/un;
  float pn = t1;
  if (pn > MAXN_P){ sc *= MAXN_P/pn; pn = MAXN_P; }
  float ln = fmaxf(pn, 1e-15f);
  float m = sc * (artanh_c(ln)/ln);
  float v[K]; float vs = 0.f;
  #pragma unroll
  for(int k=0;k<K;k++){ v[k] = fmaxf(u[k]*m, 0.f); vs += v[k]*v[k]; }
  vs = gredw<W>(vs);
  float vn = fmaxf(sqrtf(vs), 1e-15f);
  float t2 = tanhf(vn);
  float qs = t2/vn;
  float qn = t2;
  if (qn > MAXN_P){ qs *= MAXN_P/qn; qn = MAXN_P; }
  #pragma unroll
  for(int k=0;k<K;k++) h[k] = v[k]*qs;
  return qn;
}

// ---------------- fused prologue: exp0 | hist | w2bf(W0) | w2bf(W1) | hb ----------------
__global__ __launch_bounds__(256) void k_prologue(
    const float* __restrict__ x, bfraw* __restrict__ h0, float* __restrict__ n0, int N,
    const int* __restrict__ dst, int* __restrict__ cnt, int E,
    const float* __restrict__ W0, bfraw* __restrict__ w0b, int nW0,
    const float* __restrict__ W1, bfraw* __restrict__ w1b, int nW1,
    const float* __restrict__ b0, const float* __restrict__ b1,
    float* __restrict__ hb0, float* __restrict__ hb1, int HID, int DIM,
    int RB, int HIST, int W0B, int W1B)
{
  int b = blockIdx.x;
  int tid = threadIdx.x;
  if (b < RB){
    int wid = (b*256 + tid)>>6;
    int lane = tid & 63;
    if (wid >= N) return;
    const float* r = x + (size_t)wid*128;
    float u0 = r[lane], u1 = r[lane+64];
    float ss = wred(u0*u0 + u1*u1);
    float un = fmaxf(sqrtf(ss), 1e-15f);
    float tn = tanhf(un);
    float sc = tn/un;
    float pn = tn;
    if (pn > MAXN_P){ sc *= MAXN_P/pn; pn = MAXN_P; }
    h0[(size_t)wid*128 + lane]      = f2bf(u0*sc);
    h0[(size_t)wid*128 + lane + 64] = f2bf(u1*sc);
    if (lane == 0) n0[wid] = pn;
    return;
  }
  b -= RB;
  if (b < HIST){
    int e = b*256 + tid;
    if (e < E) atomicAdd(&cnt[dst[e]], 1);
    return;
  }
  b -= HIST;
  if (b < W0B){
    int i = b*256 + tid;
    if (i < nW0) w0b[i] = f2bf(W0[i]);
    return;
  }
  b -= W0B;
  if (b < W1B){
    int i = b*256 + tid;
    if (i < nW1) w1b[i] = f2bf(W1[i]);
    return;
  }
  b -= W1B;
  {
    if (tid >= 64) return;
    int layer = b >> 2, br = b & 3;
    int D = layer ? DIM : HID;
    const float* bb = layer ? (b1 + (size_t)br*DIM) : (b0 + (size_t)br*HID);
    float* o        = layer ? (hb1 + (size_t)br*DIM) : (hb0 + (size_t)br*HID);
    float v0 = (tid < D) ? bb[tid] : 0.f;
    float v1 = (tid+64 < D) ? bb[tid+64] : 0.f;
    float ss = wred(v0*v0 + v1*v1);
    float n = fmaxf(sqrtf(ss), 1e-15f);
    float tn = tanhf(n);
    float sc = tn/n;
    if (tn > MAXN_P) sc *= MAXN_P/tn;
    if (tid < D)    o[tid]    = v0*sc;
    if (tid+64 < D) o[tid+64] = v1*sc;
  }
}

// ---------------- hierarchical scan: cnt[N] -> rowptr[N+1], cursor[N] ----------------
__global__ __launch_bounds__(256) void k_scan1(const int* __restrict__ cnt, int* __restrict__ bsum, int N){
  __shared__ int sh[256];
  int base = blockIdx.x*2048;
  int tid = threadIdx.x;
  int loc = 0;
  #pragma unroll
  for(int j=0;j<8;j++){
    int i = base + tid*8 + j;
    loc += (i < N) ? cnt[i] : 0;
  }
  sh[tid] = loc;
  __syncthreads();
  for(int off=128; off>0; off>>=1){
    if (tid < off) sh[tid] += sh[tid+off];
    __syncthreads();
  }
  if (tid == 0) bsum[blockIdx.x] = sh[0];
}
// scan23: block-local exclusive scan; base computed by serially scanning bsum[0..blockIdx) (nb<=25)
__global__ __launch_bounds__(256) void k_scan23(const int* __restrict__ cnt, const int* __restrict__ bsum,
                                                int* __restrict__ rowptr, int* __restrict__ cursor, int N){
  __shared__ int sh[256];
  __shared__ int sbase;
  int tid = threadIdx.x;
  if (tid == 0){
    int run = 0;
    for(int i=0;i<(int)blockIdx.x;i++) run += bsum[i];
    sbase = run;
  }
  int base = blockIdx.x*2048;
  int v[8]; int loc = 0;
  #pragma unroll
  for(int j=0;j<8;j++){
    int i = base + tid*8 + j;
    v[j] = (i < N) ? cnt[i] : 0;
    loc += v[j];
  }
  sh[tid] = loc;
  __syncthreads();
  for(int off=1; off<256; off<<=1){
    int add = (tid>=off) ? sh[tid-off] : 0;
    __syncthreads();
    sh[tid] += add;
    __syncthreads();
  }
  int run = ((tid==0) ? 0 : sh[tid-1]) + sbase;
  #pragma unroll
  for(int j=0;j<8;j++){
    int i = base + tid*8 + j;
    if (i < N){
      rowptr[i] = run; cursor[i] = run; run += v[j];
      if (i == N-1) rowptr[N] = run;
    }
  }
}

// -------- fused: CSR fill (role A) | MFMA GEMM layer0 + post epilogue (role B) --------
// Independent work items; fused so the scatter latency hides under GEMM throughput.
__global__ __launch_bounds__(256) void k_fill_gemm0(
    // fill args
    const int* __restrict__ src, const int* __restrict__ dst,
    const float* __restrict__ ew, int E,
    int* __restrict__ cursor, int* __restrict__ srcs, float4* __restrict__ wq,
    int FILLB,
    // gemm args (CT=8, BN=128)
    const bfraw* __restrict__ Abase,
    const bfraw* __restrict__ Wb,
    const float* __restrict__ nin,
    const float* __restrict__ hball,
    bfraw* __restrict__ xt,
    int M, int GX)
{
  constexpr int CT = 8;
  constexpr int BN = CT*16;
  __shared__ bfraw tile[64*BN];
  int blk = blockIdx.x;
  int t = threadIdx.x;
  if (blk < FILLB){
    int e = blk*256 + t;
    if (e >= E) return;
    int d = dst[e];
    int pos = atomicAdd(&cursor[d], 1);
    srcs[pos] = src[e];
    wq[pos] = make_float4(ew[e], ew[(size_t)E + e], ew[2*(size_t)E + e], ew[3*(size_t)E + e]);
    return;
  }
  int bb = blk - FILLB;
  int br = bb / GX;
  int rb = (bb - br*GX) * 64;
  const bfraw* A = Abase;                       // layer0: abroff=0
  const bfraw* W = Wb + (size_t)br*BN*128;
  const float* hb = hball + (size_t)br*BN;
  int wave = t>>6, lane = t&63;
  int cl = lane&15, grp = lane>>4;

  int rowA = rb + wave*16 + cl;
  bf16x8 afr[4];
  bf16x8 zf = {0,0,0,0,0,0,0,0};
  #pragma unroll
  for(int ks=0;ks<4;ks++){
    if (rowA < M) afr[ks] = *(const bf16x8*)(A + (size_t)rowA*128 + ks*32 + grp*8);
    else          afr[ks] = zf;
  }
  f32x4 acc[CT];
  #pragma unroll
  for(int ct=0;ct<CT;ct++) acc[ct] = f32x4{0.f,0.f,0.f,0.f};
  #pragma unroll
  for(int ct=0;ct<CT;ct++){
    #pragma unroll
    for(int ks=0;ks<4;ks++){
      bf16x8 bfr = *(const bf16x8*)(W + (size_t)(ct*16+cl)*128 + ks*32 + grp*8);
      acc[ct] = __builtin_amdgcn_mfma_f32_16x16x32_bf16(afr[ks], bfr, acc[ct], 0,0,0);
    }
  }
  float hv[CT]; float hb2 = 0.f;
  #pragma unroll
  for(int ct=0;ct<CT;ct++){ hv[ct] = hb[cl+16*ct]; hb2 += hv[ct]*hv[ct]; }
  hb2 = gredw<16>(hb2);
  #pragma unroll
  for(int j=0;j<4;j++){
    int rloc = wave*16 + grp*4 + j;
    int node = rb + rloc;
    bool v = node < M;
    float m[CT]; float ss = 0.f;
    #pragma unroll
    for(int ct=0;ct<CT;ct++){ m[ct] = acc[ct][j]; ss += m[ct]*m[ct]; }
    ss = gredw<16>(ss);
    float mxn_raw = sqrtf(ss);
    float mxn = fmaxf(mxn_raw, 1e-15f);
    float xn = fmaxf(v ? nin[node] : 1.f, 1e-15f);
    float th = tanhf(mxn/xn * artanh_c(xn));
    float hs = (mxn_raw > 0.f) ? th/mxn : 0.f;
    float hn = (mxn_raw > 0.f) ? th : 0.f;
    if (hn > MAXN_P){ hs *= MAXN_P/hn; hn = MAXN_P; }
    float h[CT]; float xy = 0.f, x2 = 0.f;
    #pragma unroll
    for(int ct=0;ct<CT;ct++){ h[ct] = m[ct]*hs; xy += h[ct]*hv[ct]; x2 += h[ct]*h[ct]; }
    xy = gredw<16>(xy); x2 = gredw<16>(x2);
    float c1 = 1.f + 2.f*xy + hb2;
    float c2 = 1.f - x2;
    float den = fmaxf(1.f + 2.f*xy + x2*hb2, 1e-15f);
    float a[CT]; float as = 0.f;
    #pragma unroll
    for(int ct=0;ct<CT;ct++){ a[ct] = (c1*h[ct] + c2*hv[ct])/den; as += a[ct]*a[ct]; }
    as = gredw<16>(as);
    float an = fmaxf(sqrtf(as), 1e-15f);
    float s2 = 1.f;
    if (an > MAXN_P){ s2 = MAXN_P/an; an = MAXN_P; }
    float ls = artanh_c(an)/an * s2;
    #pragma unroll
    for(int ct=0;ct<CT;ct++) tile[rloc*BN + cl + 16*ct] = f2bf(a[ct]*ls);
  }
  __syncthreads();
  constexpr int IT = (64*BN)/(256*8);
  #pragma unroll
  for(int i=0;i<IT;i++){
    int flat = (t + i*256)*8;
    int row = flat/BN, col = flat%BN;
    int node = rb + row;
    if (node < M)
      *(uint4*)(xt + ((size_t)node*4 + br)*BN + col) = *(const uint4*)(tile + row*BN + col);
  }
}

// -------- MFMA bf16 GEMM (BM=64, BN=CT*16, K=128) + fused post_gemm epilogue (layer 1) --------
template<int CT>
__global__ __launch_bounds__(256) void k_gemm_fused(
    const bfraw* __restrict__ Abase, int lda, int abroff,
    const bfraw* __restrict__ Wb,          // [4][BN][128] bf16
    const float* __restrict__ nin, int nstride, int nbroff,
    const float* __restrict__ hball,       // [4][BN] f32
    bfraw* __restrict__ xt,                // [M][4][BN] bf16
    int M)
{
  constexpr int BN = CT*16;
  __shared__ bfraw tile[64*BN];
  int br = blockIdx.z;
  const bfraw* A = Abase + (size_t)br*abroff;
  const bfraw* W = Wb + (size_t)br*BN*128;
  const float* hb = hball + (size_t)br*BN;
  int rb = blockIdx.x*64;
  int t = threadIdx.x;
  int wave = t>>6, lane = t&63;
  int cl = lane&15, grp = lane>>4;

  int rowA = rb + wave*16 + cl;
  bf16x8 afr[4];
  bf16x8 zf = {0,0,0,0,0,0,0,0};
  #pragma unroll
  for(int ks=0;ks<4;ks++){
    if (rowA < M) afr[ks] = *(const bf16x8*)(A + (size_t)rowA*lda + ks*32 + grp*8);
    else          afr[ks] = zf;
  }
  f32x4 acc[CT];
  #pragma unroll
  for(int ct=0;ct<CT;ct++) acc[ct] = f32x4{0.f,0.f,0.f,0.f};
  #pragma unroll
  for(int ct=0;ct<CT;ct++){
    #pragma unroll
    for(int ks=0;ks<4;ks++){
      bf16x8 bfr = *(const bf16x8*)(W + (size_t)(ct*16+cl)*128 + ks*32 + grp*8);
      acc[ct] = __builtin_amdgcn_mfma_f32_16x16x32_bf16(afr[ks], bfr, acc[ct], 0,0,0);
    }
  }
  float hv[CT]; float hb2 = 0.f;
  #pragma unroll
  for(int ct=0;ct<CT;ct++){ hv[ct] = hb[cl+16*ct]; hb2 += hv[ct]*hv[ct]; }
  hb2 = gredw<16>(hb2);
  #pragma unroll
  for(int j=0;j<4;j++){
    int rloc = wave*16 + grp*4 + j;
    int node = rb + rloc;
    bool v = node < M;
    float m[CT]; float ss = 0.f;
    #pragma unroll
    for(int ct=0;ct<CT;ct++){ m[ct] = acc[ct][j]; ss += m[ct]*m[ct]; }
    ss = gredw<16>(ss);
    float mxn_raw = sqrtf(ss);
    float mxn = fmaxf(mxn_raw, 1e-15f);
    float xn = fmaxf(v ? nin[(size_t)node*nstride + br*nbroff] : 1.f, 1e-15f);
    float th = tanhf(mxn/xn * artanh_c(xn));
    float hs = (mxn_raw > 0.f) ? th/mxn : 0.f;
    float hn = (mxn_raw > 0.f) ? th : 0.f;
    if (hn > MAXN_P){ hs *= MAXN_P/hn; hn = MAXN_P; }
    float h[CT]; float xy = 0.f, x2 = 0.f;
    #pragma unroll
    for(int ct=0;ct<CT;ct++){ h[ct] = m[ct]*hs; xy += h[ct]*hv[ct]; x2 += h[ct]*h[ct]; }
    xy = gredw<16>(xy); x2 = gredw<16>(x2);
    float c1 = 1.f + 2.f*xy + hb2;
    float c2 = 1.f - x2;
    float den = fmaxf(1.f + 2.f*xy + x2*hb2, 1e-15f);
    float a[CT]; float as = 0.f;
    #pragma unroll
    for(int ct=0;ct<CT;ct++){ a[ct] = (c1*h[ct] + c2*hv[ct])/den; as += a[ct]*a[ct]; }
    as = gredw<16>(as);
    float an = fmaxf(sqrtf(as), 1e-15f);
    float s2 = 1.f;
    if (an > MAXN_P){ s2 = MAXN_P/an; an = MAXN_P; }
    float ls = artanh_c(an)/an * s2;
    #pragma unroll
    for(int ct=0;ct<CT;ct++) tile[rloc*BN + cl + 16*ct] = f2bf(a[ct]*ls);
  }
  __syncthreads();
  constexpr int IT = (64*BN)/(256*8);
  #pragma unroll
  for(int i=0;i<IT;i++){
    int flat = (t + i*256)*8;
    int row = flat/BN, col = flat%BN;
    int node = rb + row;
    if (node < M)
      *(uint4*)(xt + ((size_t)node*4 + br)*BN + col) = *(const uint4*)(tile + row*BN + col);
  }
}

// -------- fused 4-branch spmm layer0 (bf16 table, 1KB/row, depth-8, f32 weights) --------
__global__ __launch_bounds__(256) void k_spmm_l0(const int* __restrict__ rowptr,
                        const int* __restrict__ srcs, const float4* __restrict__ wq,
                        const bfraw* __restrict__ xt,
                        bfraw* __restrict__ hout, float* __restrict__ n4, int N){
  int wid = (blockIdx.x*blockDim.x + threadIdx.x)>>6;
  int lane = threadIdx.x & 63;
  if (wid >= N) return;
  int g = lane>>4;               // branch (16-lane groups, 8 dims/lane)
  float acc[8] = {0,0,0,0,0,0,0,0};
  int p0 = rowptr[wid], p1 = rowptr[wid+1];
  int p = p0;
  for (; p+8 <= p1; p += 8){
    int s[8]; float4 w[8]; uint4 u[8];
    #pragma unroll
    for(int i=0;i<8;i++){ s[i] = srcs[p+i]; w[i] = wq[p+i]; }
    #pragma unroll
    for(int i=0;i<8;i++) u[i] = *((const uint4*)(xt + (size_t)s[i]*512) + lane);
    #pragma unroll
    for(int i=0;i<8;i++) acc8(acc, sel4(w[i],g), u[i]);
  }
  for (; p+2 <= p1; p += 2){
    int s0 = srcs[p], s1 = srcs[p+1];
    float4 w0 = wq[p], w1 = wq[p+1];
    uint4 u0 = *((const uint4*)(xt + (size_t)s0*512) + lane);
    uint4 u1 = *((const uint4*)(xt + (size_t)s1*512) + lane);
    acc8(acc, sel4(w0,g), u0);
    acc8(acc, sel4(w1,g), u1);
  }
  if (p < p1){
    int s0 = srcs[p];
    float4 w0 = wq[p];
    uint4 u0 = *((const uint4*)(xt + (size_t)s0*512) + lane);
    acc8(acc, sel4(w0,g), u0);
  }
  float h[8];
  float qn = postK<16,8>(acc, h);
  uint4 o;
  o.x = (unsigned)f2bf(h[0]) | ((unsigned)f2bf(h[1])<<16);
  o.y = (unsigned)f2bf(h[2]) | ((unsigned)f2bf(h[3])<<16);
  o.z = (unsigned)f2bf(h[4]) | ((unsigned)f2bf(h[5])<<16);
  o.w = (unsigned)f2bf(h[6]) | ((unsigned)f2bf(h[7])<<16);
  *((uint4*)(hout + (size_t)wid*512) + lane) = o;
  if ((lane&15)==0) n4[(size_t)wid*4 + g] = qn;
}

// -------- fused 4-branch spmm layer1: TWO dst rows per wave + post + Mobius combine --------
__global__ __launch_bounds__(256) void k_spmm_l1(const int* __restrict__ rowptr,
                        const int* __restrict__ srcs, const float4* __restrict__ wq,
                        const bfraw* __restrict__ xt,
                        float* __restrict__ out, int N){
  int wpair = (blockIdx.x*blockDim.x + threadIdx.x)>>6;
  int lane = threadIdx.x & 63;
  int half = lane>>5;            // 0: row 2w, 1: row 2w+1
  int l31 = lane & 31;
  int row = wpair*2 + half;
  bool rv = row < N;
  int rc = rv ? row : 0;
  int p0 = rowptr[rc];
  int p1 = rv ? rowptr[rc+1] : p0;
  int deg = p1 - p0;
  int mx = deg;
  #pragma unroll
  for(int o=32;o>0;o>>=1) mx = max(mx, __shfl_xor(mx, o, 64));
  int g = l31 >> 3;              // branch (8-lane groups, 8 dims/lane)
  int slot = l31 & 7;
  float acc[8] = {0,0,0,0,0,0,0,0};
  for (int i = 0; i < mx; i += 4){
    int pe[4]; float wv[4]; uint4 u[4];
    #pragma unroll
    for(int j=0;j<4;j++){
      int pi = p0 + i + j;
      bool v = pi < p1;
      pe[j] = v ? pi : 0;
      wv[j] = v ? 1.f : 0.f;
    }
    int s[4]; float4 w4[4];
    #pragma unroll
    for(int j=0;j<4;j++){ s[j] = srcs[pe[j]]; w4[j] = wq[pe[j]]; }
    #pragma unroll
    for(int j=0;j<4;j++) u[j] = *((const uint4*)(xt + (size_t)s[j]*256) + l31);
    #pragma unroll
    for(int j=0;j<4;j++) acc8(acc, wv[j]*sel4(w4[j],g), u[j]);
  }
  float h[8];
  float qn = postK<8,8>(acc, h);
  int hb = half*32;
  float t[8], s[8];
  float qk0 = fmaxf(__shfl(qn, hb + 0, 64), 1e-15f);
  float lk0 = artanh_c(qk0)/qk0;
  float s0 = tanhf(0.125f*artanh_c(qk0))/qk0;
  #pragma unroll
  for(int j=0;j<8;j++){
    float xv = __shfl(h[j], hb + slot, 64);   // branch 0
    t[j] = s0*xv;
    s[j] = lk0*xv;
  }
  #pragma unroll
  for(int k=1;k<4;k++){
    float qk = fmaxf(__shfl(qn, hb + k*8, 64), 1e-15f);
    float lk = artanh_c(qk)/qk;
    float sy = tanhf(0.125f*artanh_c(qk))/qk;
    float y[8];
    float dx=0.f, dy=0.f, dxy=0.f;
    #pragma unroll
    for(int j=0;j<8;j++){
      float xv = __shfl(h[j], hb + k*8 + slot, 64);
      y[j] = sy*xv;
      s[j] = fmaf(lk, xv, s[j]);
      dx += t[j]*t[j]; dy += y[j]*y[j]; dxy += t[j]*y[j];
    }
    float x2 = gredw<8>(dx);
    float y2 = gredw<8>(dy);
    float xy = gredw<8>(dxy);
    float c1 = 1.f + 2.f*xy + y2;
    float c2 = 1.f - x2;
    float den = fmaxf(1.f + 2.f*xy + x2*y2, 1e-15f);
    #pragma unroll
    for(int j=0;j<8;j++) t[j] = (c1*t[j] + c2*y[j])/den;
  }
  float dt = 0.f;
  #pragma unroll
  for(int j=0;j<8;j++) dt += t[j]*t[j];
  float tn = fmaxf(sqrtf(gredw<8>(dt)), 1e-15f);
  float lt = artanh_c(tn)/tn;
  #pragma unroll
  for(int j=0;j<8;j++) s[j] = 0.2f*fmaf(lt, t[j], s[j]);
  float ds = 0.f;
  #pragma unroll
  for(int j=0;j<8;j++) ds += s[j]*s[j];
  float an = fmaxf(sqrtf(gredw<8>(ds)), 1e-15f);
  float on = tanhf(an);
  float osc = on/an;
  if (on > MAXN_P) osc *= MAXN_P/on;
  if (g == 0 && rv){
    float* orow = out + (size_t)row*64 + slot*8;
    *(float4*)(orow)     = make_float4(s[0]*osc, s[1]*osc, s[2]*osc, s[3]*osc);
    *(float4*)(orow + 4) = make_float4(s[4]*osc, s[5]*osc, s[6]*osc, s[7]*osc);
  }
}

extern "C" void kernel_launch(void* const* d_in, const int* in_sizes, int n_in,
                              void* d_out, int out_size, void* d_ws, size_t ws_size,
                              hipStream_t stream){
  const float* x   = (const float*)d_in[0];
  const int*   src = (const int*)d_in[1];
  const int*   dst = (const int*)d_in[2];
  const float* ew  = (const float*)d_in[3];   // [4,E]
  const float* W0  = (const float*)d_in[4];   // [4,HID,128]
  const float* b0  = (const float*)d_in[5];   // [4,HID]
  const float* W1  = (const float*)d_in[6];   // [4,DIM,HID]
  const float* b1  = (const float*)d_in[7];   // [4,DIM]
  float* out = (float*)d_out;

  const int FIN = 128;
  int N = in_sizes[0]/FIN;
  int E = in_sizes[1];
  int HID = in_sizes[5]/4;   // 128
  int DIM = in_sizes[7]/4;   // 64

  char* ws = (char*)d_ws;
  size_t off = 0;
  auto alloc = [&](size_t bytes)->char*{
    char* p = ws + off;
    off += (bytes + 255) & ~(size_t)255;
    return p;
  };
  bfraw* h4b    = (bfraw*)alloc((size_t)N*4*FIN*2);   // h4 bf16; prefix aliased as h0 bf16
  bfraw* xtb    = (bfraw*)alloc((size_t)N*4*FIN*2);   // bf16 gather tables (l0 full, l1 half)
  float* n0     = (float*)alloc((size_t)N*4);
  float* n4     = (float*)alloc((size_t)N*16);
  int*   rowptr = (int*)alloc((size_t)(N+1)*4);
  int*   cnt    = (int*)alloc((size_t)N*4);
  int*   cursor = (int*)alloc((size_t)N*4);
  int*   srcs   = (int*)alloc((size_t)E*4);
  float4* wq    = (float4*)alloc((size_t)E*16);
  float* hb0    = (float*)alloc((size_t)4*HID*4);
  float* hb1    = (float*)alloc((size_t)4*DIM*4);
  bfraw* w0b    = (bfraw*)alloc((size_t)4*HID*FIN*2);
  bfraw* w1b    = (bfraw*)alloc((size_t)4*DIM*HID*2);
  int*   bsum   = (int*)alloc((size_t)256*4);
  (void)ws_size; (void)n_in; (void)out_size;

  bfraw* h0 = h4b;   // h0 dead (after GEMM0) before spmm_l0 writes h4b

  int rowBlocks = (N + 3)/4;       // wave per node
  int pairBlocks = (N + 7)/8;      // wave per 2 nodes (spmm_l1)
  int nW0 = 4*HID*FIN, nW1 = 4*DIM*HID;
  int RB = rowBlocks;
  int HIST = (E + 255)/256;
  int W0B = (nW0 + 255)/256;
  int W1B = (nW1 + 255)/256;
  int nscan = (N + 2047)/2048;
  int GX = (N + 63)/64;

  // fused prologue (exp0 | hist | w2bf x2 | hb), after cnt memset
  hipMemsetAsync(cnt, 0, (size_t)N*4, stream);
  k_prologue<<<RB + HIST + W0B + W1B + 8, 256, 0, stream>>>(
      x, h0, n0, N, dst, cnt, E, W0, w0b, nW0, W1, w1b, nW1,
      b0, b1, hb0, hb1, HID, DIM, RB, HIST, W0B, W1B);

  // hierarchical scan -> rowptr/cursor
  k_scan1<<<nscan, 256, 0, stream>>>(cnt, bsum, N);
  k_scan23<<<nscan, 256, 0, stream>>>(cnt, bsum, rowptr, cursor, N);

  // fused: CSR fill || layer-0 MFMA GEMM + post (independent work, overlapped)
  k_fill_gemm0<<<HIST + GX*4, 256, 0, stream>>>(
      src, dst, ew, E, cursor, srcs, wq, HIST,
      h0, w0b, n0, hb0, xtb, N, GX);

  // layer 0 spmm (+post, bf16 out)
  k_spmm_l0<<<rowBlocks, 256, 0, stream>>>(rowptr, srcs, wq, xtb, h4b, n4, N);

  // layer 1: MFMA GEMM + fused post -> fused spmm(+post+combine, 2 rows/wave) -> out
  k_gemm_fused<4><<<dim3(GX, 1, 4), 256, 0, stream>>>(
      h4b, 4*HID, HID, w1b, n4, 4, 1, hb1, xtb, N);
  k_spmm_l1<<<pairBlocks, 256, 0, stream>>>(rowptr, srcs, wq, xtb, out, N);
}